// Round 1
// baseline (267.701 us; speedup 1.0000x reference)
//
#include <hip/hip_runtime.h>
#include <math.h>

#define DIMD 128
#define POSLEN 2048
#define EDGEPOS 4096

__device__ __forceinline__ double wave_reduce_add_d(double v) {
    #pragma unroll
    for (int m = 32; m >= 1; m >>= 1) v += __shfl_xor(v, m, 64);
    return v;
}
__device__ __forceinline__ float wave_reduce_add_f(float v) {
    #pragma unroll
    for (int m = 32; m >= 1; m >>= 1) v += __shfl_xor(v, m, 64);
    return v;
}

// ws layout: ws_d[0] = sum exp(10*s - 10) over negative scores
//            ws_d[1] = sum exp(10*x)      over negative edge probs
//            ws_f at byte 16: inv_qnorm
__global__ void k0_init(const float* __restrict__ q, double* __restrict__ ws_d,
                        float* __restrict__ ws_f) {
    int l = threadIdx.x;  // 64 threads, one wave
    float2 qv = ((const float2*)q)[l];
    float s = qv.x * qv.x + qv.y * qv.y;
    s = wave_reduce_add_f(s);
    if (l == 0) {
        ws_d[0] = 0.0;
        ws_d[1] = 0.0;
        ws_f[0] = 1.0f / fmaxf(sqrtf(s), 1e-12f);
    }
}

// One wave per row: lane i holds row[2i], row[2i+1]; butterfly-reduce dot & norm2.
__global__ __launch_bounds__(256) void k1_scores(
        const float* __restrict__ feat, const float* __restrict__ q,
        float* __restrict__ scores_out, double* __restrict__ ws_d,
        const float* __restrict__ ws_f, int nrows) {
    const int lane = threadIdx.x & 63;
    const int wave = (blockIdx.x * blockDim.x + threadIdx.x) >> 6;
    const int nwaves = (gridDim.x * blockDim.x) >> 6;
    const float2 qv = ((const float2*)q)[lane];
    const float invq = ws_f[0];

    double acc = 0.0;   // per-wave partial of sum exp(10s-10) over negatives
    float facc = 0.0f;  // cheap float accumulation between flushes
    int fcnt = 0;
    for (int r = wave; r < nrows; r += nwaves) {
        const float2 f = ((const float2*)(feat + (size_t)r * DIMD))[lane];
        float dot = f.x * qv.x + f.y * qv.y;
        float n2  = f.x * f.x + f.y * f.y;
        #pragma unroll
        for (int m = 32; m >= 1; m >>= 1) {
            dot += __shfl_xor(dot, m, 64);
            n2  += __shfl_xor(n2, m, 64);
        }
        if (lane == 0) {
            float s = dot * (1.0f / fmaxf(sqrtf(n2), 1e-12f)) * invq;
            scores_out[r] = s;
            if (r >= POSLEN) {
                facc += __expf(10.0f * s - 10.0f) ;
                if (++fcnt == 16) { acc += (double)facc; facc = 0.0f; fcnt = 0; }
            }
        }
    }
    if (lane == 0) {
        acc += (double)facc;
        if (acc != 0.0) atomicAdd(&ws_d[0], acc);
    }
}

// Negative edges: sum exp(10*x) in double (10*x <= ~50, fine for expf -> double acc).
__global__ __launch_bounds__(256) void k2_edges(const float* __restrict__ ep,
                                                int total, double* __restrict__ ws_d) {
    double acc = 0.0;
    for (int i = blockIdx.x * blockDim.x + threadIdx.x; i < total;
         i += gridDim.x * blockDim.x) {
        acc += (double)expf(10.0f * ep[EDGEPOS + i]);
    }
    acc = wave_reduce_add_d(acc);
    if ((threadIdx.x & 63) == 0) atomicAdd(&ws_d[1], acc);
}

// Finalize: lse of negatives, then mean over positives of logaddexp(10p, lse) - 10p.
__global__ __launch_bounds__(256) void k3_final(
        const float* __restrict__ scores, const float* __restrict__ ep,
        const double* __restrict__ ws_d, float* __restrict__ out0,
        float* __restrict__ out_c, float* __restrict__ out_lp) {
    __shared__ double sh1[4], sh2[4];
    const double lse_s = 10.0 + log(ws_d[0]);
    const double lse_e = log(ws_d[1]);
    double a1 = 0.0, a2 = 0.0;
    for (int i = threadIdx.x; i < POSLEN; i += blockDim.x) {
        double p = (double)scores[i] * 10.0;
        double m = fmax(p, lse_s);
        a1 += m + log1p(exp(fmin(p, lse_s) - m)) - p;
    }
    for (int i = threadIdx.x; i < EDGEPOS; i += blockDim.x) {
        double p = (double)ep[i] * 10.0;
        double m = fmax(p, lse_e);
        a2 += m + log1p(exp(fmin(p, lse_e) - m)) - p;
    }
    a1 = wave_reduce_add_d(a1);
    a2 = wave_reduce_add_d(a2);
    int w = threadIdx.x >> 6;
    if ((threadIdx.x & 63) == 0) { sh1[w] = a1; sh2[w] = a2; }
    __syncthreads();
    if (threadIdx.x == 0) {
        double c = (sh1[0] + sh1[1] + sh1[2] + sh1[3]) / (double)POSLEN;
        double l = (sh2[0] + sh2[1] + sh2[2] + sh2[3]) / (double)EDGEPOS;
        *out0  = (float)(c + 0.1 * l);
        *out_c = (float)c;
        *out_lp = (float)l;
    }
}

extern "C" void kernel_launch(void* const* d_in, const int* in_sizes, int n_in,
                              void* d_out, int out_size, void* d_ws, size_t ws_size,
                              hipStream_t stream) {
    const float* feat = (const float*)d_in[0];
    const float* q    = (const float*)d_in[1];
    const float* ep   = (const float*)d_in[2];
    const int N = in_sizes[0] / DIMD;
    const int E = in_sizes[2];

    float* out = (float*)d_out;           // [0]=outlier, [1..N]=scores, [N+1]=contras, [N+2]=lp
    double* ws_d = (double*)d_ws;
    float* ws_f  = (float*)((char*)d_ws + 16);

    hipLaunchKernelGGL(k0_init, dim3(1), dim3(64), 0, stream, q, ws_d, ws_f);
    hipLaunchKernelGGL(k1_scores, dim3(512), dim3(256), 0, stream,
                       feat, q, out + 1, ws_d, ws_f, N);
    hipLaunchKernelGGL(k2_edges, dim3(128), dim3(256), 0, stream,
                       ep, E - EDGEPOS, ws_d);
    hipLaunchKernelGGL(k3_final, dim3(1), dim3(256), 0, stream,
                       out + 1, ep, ws_d, out, out + 1 + N, out + 2 + N);
}

// Round 2
// 205.725 us; speedup vs baseline: 1.3013x; 1.3013x over previous
//
#include <hip/hip_runtime.h>
#include <math.h>

#define DIMD 128
#define POSLEN 2048
#define EDGEPOS 4096
#define SBLK 2048   // blocks doing scores
#define EBLK 64     // blocks doing negative edges

__device__ __forceinline__ double wave_reduce_add_d(double v) {
    #pragma unroll
    for (int m = 32; m >= 1; m >>= 1) v += __shfl_xor(v, m, 64);
    return v;
}

// ws_d[0] = sum exp(10*s - 10) over negative scores
// ws_d[1] = sum exp(10*x)      over negative edge probs
__global__ __launch_bounds__(256) void k_main(
        const float* __restrict__ feat, const float* __restrict__ q,
        const float* __restrict__ ep, int nrows, int nedge,
        float* __restrict__ scores_out, double* __restrict__ ws_d) {
    __shared__ double sh[4];
    const int tid  = threadIdx.x;
    const int lane = tid & 63;
    const int wv   = tid >> 6;

    if (blockIdx.x < SBLK) {
        // ---- cosine scores: half-wave (32 lanes) per row, float4 per lane ----
        const int hl = lane & 31;
        const float4 qv = ((const float4*)q)[hl];
        float qn2 = qv.x*qv.x + qv.y*qv.y + qv.z*qv.z + qv.w*qv.w;
        #pragma unroll
        for (int m = 16; m >= 1; m >>= 1) qn2 += __shfl_xor(qn2, m, 64);
        const float invq = 1.0f / fmaxf(sqrtf(qn2), 1e-12f);

        // global half-wave id -> row; wave covers rows (r, r+1) = 1KB contiguous
        const int h = ((blockIdx.x * 4 + wv) << 1) + (lane >> 5);
        const int H = SBLK * 8;
        float facc = 0.0f;
        double acc = 0.0;
        int fcnt = 0;
        for (int r = h; r < nrows; r += H) {
            const float4 f = ((const float4*)(feat + (size_t)r * DIMD))[hl];
            float dot = f.x*qv.x + f.y*qv.y + f.z*qv.z + f.w*qv.w;
            float n2  = f.x*f.x + f.y*f.y + f.z*f.z + f.w*f.w;
            #pragma unroll
            for (int m = 16; m >= 1; m >>= 1) {
                dot += __shfl_xor(dot, m, 64);
                n2  += __shfl_xor(n2, m, 64);
            }
            if (hl == 0) {
                float s = dot * (1.0f / fmaxf(sqrtf(n2), 1e-12f)) * invq;
                scores_out[r] = s;
                if (r >= POSLEN) {
                    facc += __expf(10.0f * s - 10.0f);   // in (0, 1]; no overflow
                    if (++fcnt == 16) { acc += (double)facc; facc = 0.0f; fcnt = 0; }
                }
            }
        }
        acc += (double)facc;
        acc += __shfl_xor(acc, 32, 64);       // combine the two half-wave leaders
        if (lane == 0) sh[wv] = acc;
        __syncthreads();
        if (tid == 0) {
            double t = sh[0] + sh[1] + sh[2] + sh[3];
            if (t != 0.0) atomicAdd(&ws_d[0], t);
        }
    } else {
        // ---- negative edge probs: sum exp(10x), float4 grid-stride ----
        const int nedge4 = nedge >> 2;
        const float4* p4 = (const float4*)(ep + EDGEPOS);
        double acc = 0.0;
        for (int i = (blockIdx.x - SBLK) * 256 + tid; i < nedge4; i += EBLK * 256) {
            float4 v = p4[i];
            acc += (double)__expf(10.0f * v.x) + (double)__expf(10.0f * v.y)
                 + (double)__expf(10.0f * v.z) + (double)__expf(10.0f * v.w);
        }
        if (blockIdx.x == SBLK && tid == 0) {          // scalar tail (nedge % 4)
            for (int i = nedge4 << 2; i < nedge; ++i)
                acc += (double)__expf(10.0f * ep[EDGEPOS + i]);
        }
        acc = wave_reduce_add_d(acc);
        if (lane == 0) sh[wv] = acc;
        __syncthreads();
        if (tid == 0) atomicAdd(&ws_d[1], sh[0] + sh[1] + sh[2] + sh[3]);
    }
}

// Finalize: lse of negatives, mean over positives of logaddexp(10p, lse) - 10p.
__global__ __launch_bounds__(256) void k3_final(
        const float* __restrict__ scores, const float* __restrict__ ep,
        const double* __restrict__ ws_d, float* __restrict__ out0,
        float* __restrict__ out_c, float* __restrict__ out_lp) {
    __shared__ double sh1[4], sh2[4];
    const double lse_s = 10.0 + log(ws_d[0]);
    const double lse_e = log(ws_d[1]);
    double a1 = 0.0, a2 = 0.0;
    for (int i = threadIdx.x; i < POSLEN; i += blockDim.x) {
        double p = (double)scores[i] * 10.0;
        double m = fmax(p, lse_s);
        a1 += m + log1p(exp(fmin(p, lse_s) - m)) - p;
    }
    for (int i = threadIdx.x; i < EDGEPOS; i += blockDim.x) {
        double p = (double)ep[i] * 10.0;
        double m = fmax(p, lse_e);
        a2 += m + log1p(exp(fmin(p, lse_e) - m)) - p;
    }
    a1 = wave_reduce_add_d(a1);
    a2 = wave_reduce_add_d(a2);
    int w = threadIdx.x >> 6;
    if ((threadIdx.x & 63) == 0) { sh1[w] = a1; sh2[w] = a2; }
    __syncthreads();
    if (threadIdx.x == 0) {
        double c = (sh1[0] + sh1[1] + sh1[2] + sh1[3]) / (double)POSLEN;
        double l = (sh2[0] + sh2[1] + sh2[2] + sh2[3]) / (double)EDGEPOS;
        *out0   = (float)(c + 0.1 * l);
        *out_c  = (float)c;
        *out_lp = (float)l;
    }
}

extern "C" void kernel_launch(void* const* d_in, const int* in_sizes, int n_in,
                              void* d_out, int out_size, void* d_ws, size_t ws_size,
                              hipStream_t stream) {
    const float* feat = (const float*)d_in[0];
    const float* q    = (const float*)d_in[1];
    const float* ep   = (const float*)d_in[2];
    const int N = in_sizes[0] / DIMD;
    const int E = in_sizes[2];

    float* out   = (float*)d_out;   // [0]=outlier, [1..N]=scores, [N+1]=contras, [N+2]=lp
    double* ws_d = (double*)d_ws;

    hipMemsetAsync(d_ws, 0, 2 * sizeof(double), stream);
    hipLaunchKernelGGL(k_main, dim3(SBLK + EBLK), dim3(256), 0, stream,
                       feat, q, ep, N, E - EDGEPOS, out + 1, ws_d);
    hipLaunchKernelGGL(k3_final, dim3(1), dim3(256), 0, stream,
                       out + 1, ep, ws_d, out, out + 1 + N, out + 2 + N);
}

// Round 3
// 199.859 us; speedup vs baseline: 1.3395x; 1.0294x over previous
//
#include <hip/hip_runtime.h>
#include <math.h>

#define DIMD 128
#define POSLEN 2048
#define EDGEPOS 4096
#define SBLK 2048   // blocks doing scores
#define EBLK 64     // blocks doing negative edges
#define NGRP (SBLK * 16)   // 16-lane row-groups total (4 waves * 4 groups per block)

__device__ __forceinline__ double wave_reduce_add_d(double v) {
    #pragma unroll
    for (int m = 32; m >= 1; m >>= 1) v += __shfl_xor(v, m, 64);
    return v;
}

// ws_d[0] = sum exp(10*s - 10) over negative scores
// ws_d[1] = sum exp(10*x)      over negative edge probs
__global__ __launch_bounds__(256) void k_main(
        const float* __restrict__ feat, const float* __restrict__ q,
        const float* __restrict__ ep, int nrows, int nedge,
        float* __restrict__ scores_out, double* __restrict__ ws_d) {
    __shared__ double sh[4];
    const int tid  = threadIdx.x;
    const int lane = tid & 63;
    const int wv   = tid >> 6;

    if (blockIdx.x < SBLK) {
        // ---- cosine scores: 16 lanes per row, 8 floats (2 x float4) per lane ----
        const int sl  = lane & 15;         // sub-lane within row group
        const int grp = lane >> 4;         // 0..3 row groups per wave
        const float4* q4 = (const float4*)q;
        const float4 qa = q4[sl];
        const float4 qb = q4[16 + sl];
        float qn2 = qa.x*qa.x + qa.y*qa.y + qa.z*qa.z + qa.w*qa.w
                  + qb.x*qb.x + qb.y*qb.y + qb.z*qb.z + qb.w*qb.w;
        #pragma unroll
        for (int m = 8; m >= 1; m >>= 1) qn2 += __shfl_xor(qn2, m, 64);
        const float invq = 1.0f / fmaxf(sqrtf(qn2), 1e-12f);

        const int g0 = blockIdx.x * 16 + wv * 4 + grp;   // global row-group id
        float facc = 0.0f;   // per-lane partial (only sl==0 lanes accumulate)
        for (int r = g0; r < nrows; r += NGRP) {
            const float4* row4 = (const float4*)(feat + (size_t)r * DIMD);
            const float4 fa = row4[sl];
            const float4 fb = row4[16 + sl];
            float dot = fa.x*qa.x + fa.y*qa.y + fa.z*qa.z + fa.w*qa.w
                      + fb.x*qb.x + fb.y*qb.y + fb.z*qb.z + fb.w*qb.w;
            float n2  = fa.x*fa.x + fa.y*fa.y + fa.z*fa.z + fa.w*fa.w
                      + fb.x*fb.x + fb.y*fb.y + fb.z*fb.z + fb.w*fb.w;
            #pragma unroll
            for (int m = 8; m >= 1; m >>= 1) {
                dot += __shfl_xor(dot, m, 64);
                n2  += __shfl_xor(n2, m, 64);
            }
            if (sl == 0) {
                float s = dot * (1.0f / fmaxf(sqrtf(n2), 1e-12f)) * invq;
                scores_out[r] = s;
                if (r >= POSLEN) facc += __expf(10.0f * s - 10.0f);  // in (0,1]
            }
        }
        double acc = wave_reduce_add_d((double)facc);  // once per wave
        if (lane == 0) sh[wv] = acc;
        __syncthreads();
        if (tid == 0) {
            double t = sh[0] + sh[1] + sh[2] + sh[3];
            if (t != 0.0) atomicAdd(&ws_d[0], t);
        }
    } else {
        // ---- negative edge probs: sum exp(10x), float4 grid-stride ----
        const int nedge4 = nedge >> 2;
        const float4* p4 = (const float4*)(ep + EDGEPOS);
        double acc = 0.0;
        for (int i = (blockIdx.x - SBLK) * 256 + tid; i < nedge4; i += EBLK * 256) {
            float4 v = p4[i];
            acc += (double)__expf(10.0f * v.x) + (double)__expf(10.0f * v.y)
                 + (double)__expf(10.0f * v.z) + (double)__expf(10.0f * v.w);
        }
        if (blockIdx.x == SBLK && tid == 0) {          // scalar tail (nedge % 4)
            for (int i = nedge4 << 2; i < nedge; ++i)
                acc += (double)__expf(10.0f * ep[EDGEPOS + i]);
        }
        acc = wave_reduce_add_d(acc);
        if (lane == 0) sh[wv] = acc;
        __syncthreads();
        if (tid == 0) atomicAdd(&ws_d[1], sh[0] + sh[1] + sh[2] + sh[3]);
    }
}

// Finalize: lse of negatives, mean over positives of logaddexp(10p, lse) - 10p.
__global__ __launch_bounds__(256) void k3_final(
        const float* __restrict__ scores, const float* __restrict__ ep,
        const double* __restrict__ ws_d, float* __restrict__ out0,
        float* __restrict__ out_c, float* __restrict__ out_lp) {
    __shared__ double sh1[4], sh2[4];
    const double lse_s = 10.0 + log(ws_d[0]);
    const double lse_e = log(ws_d[1]);
    double a1 = 0.0, a2 = 0.0;
    for (int i = threadIdx.x; i < POSLEN; i += blockDim.x) {
        double p = (double)scores[i] * 10.0;
        double m = fmax(p, lse_s);
        a1 += m + log1p(exp(fmin(p, lse_s) - m)) - p;
    }
    for (int i = threadIdx.x; i < EDGEPOS; i += blockDim.x) {
        double p = (double)ep[i] * 10.0;
        double m = fmax(p, lse_e);
        a2 += m + log1p(exp(fmin(p, lse_e) - m)) - p;
    }
    a1 = wave_reduce_add_d(a1);
    a2 = wave_reduce_add_d(a2);
    int w = threadIdx.x >> 6;
    if ((threadIdx.x & 63) == 0) { sh1[w] = a1; sh2[w] = a2; }
    __syncthreads();
    if (threadIdx.x == 0) {
        double c = (sh1[0] + sh1[1] + sh1[2] + sh1[3]) / (double)POSLEN;
        double l = (sh2[0] + sh2[1] + sh2[2] + sh2[3]) / (double)EDGEPOS;
        *out0   = (float)(c + 0.1 * l);
        *out_c  = (float)c;
        *out_lp = (float)l;
    }
}

extern "C" void kernel_launch(void* const* d_in, const int* in_sizes, int n_in,
                              void* d_out, int out_size, void* d_ws, size_t ws_size,
                              hipStream_t stream) {
    const float* feat = (const float*)d_in[0];
    const float* q    = (const float*)d_in[1];
    const float* ep   = (const float*)d_in[2];
    const int N = in_sizes[0] / DIMD;
    const int E = in_sizes[2];

    float* out   = (float*)d_out;   // [0]=outlier, [1..N]=scores, [N+1]=contras, [N+2]=lp
    double* ws_d = (double*)d_ws;

    hipMemsetAsync(d_ws, 0, 2 * sizeof(double), stream);
    hipLaunchKernelGGL(k_main, dim3(SBLK + EBLK), dim3(256), 0, stream,
                       feat, q, ep, N, E - EDGEPOS, out + 1, ws_d);
    hipLaunchKernelGGL(k3_final, dim3(1), dim3(256), 0, stream,
                       out + 1, ep, ws_d, out, out + 1 + N, out + 2 + N);
}